// Round 4
// baseline (1306.194 us; speedup 1.0000x reference)
//
#include <hip/hip_runtime.h>
#include <math.h>

#define BATCH   16384
#define HDIM    24
#define NOUTC   24
#define NHID    16
#define NSTEPS  47
#define NG      96
#define WSTRIDE 100   // padded row stride for the W_ih gather table

__global__ __launch_bounds__(64) void policy_kernel(
    const float* __restrict__ W_ih, const float* __restrict__ W_hh,
    const float* __restrict__ b_ih, const float* __restrict__ b_hh,
    const float* __restrict__ Wl,   const float* __restrict__ bl,
    const float* __restrict__ rnd,  float* __restrict__ out)
{
    // Weight staging (shared, broadcast-read):
    __shared__ float sWihB[NOUTC][WSTRIDE]; // [input col][gate]: W_ih[g][c] + b_ih[g] + b_hh[g]
    __shared__ float sBias[NG];             // b_ih + b_hh (step 0: a == 0)
    __shared__ float sWhhT[HDIM][NG];       // [k][g]
    __shared__ float sWlT[HDIM][NOUTC];     // [k][n]
    __shared__ float sBl[NOUTC];
    // Per-thread state that must be dynamically indexed:
    __shared__ float sH[HDIM][64];          // h[k] per thread (own column only)
    // Output staging for coalesced writes:
    __shared__ float sPr[64][NSTEPS + 2];   // stride 49 -> conflict-spread cols
    __shared__ float sAct[64][NSTEPS + 2];

    const int tid = threadIdx.x;

    for (int i = tid; i < NG * HDIM; i += 64) {
        int g = i / HDIM, c = i % HDIM;
        float bsum = b_ih[g] + b_hh[g];
        sWihB[c][g] = W_ih[i] + bsum;   // column-select table with bias folded in
        sWhhT[c][g] = W_hh[i];          // transpose: [k][g]
    }
    for (int i = tid; i < NOUTC * HDIM; i += 64) {
        int n = i / HDIM, k = i % HDIM;
        sWlT[k][n] = Wl[i];
    }
    for (int i = tid; i < NG; i += 64) sBias[i] = b_ih[i] + b_hh[i];
    if (tid < NOUTC) sBl[tid] = bl[tid];

    float* hcol = &sH[0][tid];              // own column; rows stride 64 floats
    #pragma unroll
    for (int k = 0; k < HDIM; ++k) hcol[k * 64] = 0.f;
    float c_state[HDIM];
    #pragma unroll
    for (int j = 0; j < HDIM; ++j) c_state[j] = 0.f;

    __syncthreads();

    const int b = blockIdx.x * 64 + tid;
    int act = 0;

    for (int s = 0; s < NSTEPS; ++s) {
        // ---- gates = (W_ih[:,act] + b_ih + b_hh) + W_hh @ h ----
        float acc[NG];
        if (s == 0) {
            #pragma unroll
            for (int g4 = 0; g4 < NG; g4 += 4) {
                float4 bb = *(const float4*)&sBias[g4];
                acc[g4+0] = bb.x; acc[g4+1] = bb.y; acc[g4+2] = bb.z; acc[g4+3] = bb.w;
            }
        } else {
            const float* wrow = &sWihB[act][0];
            #pragma unroll
            for (int g4 = 0; g4 < NG; g4 += 4) {
                float4 ww = *(const float4*)&wrow[g4];        // per-lane act row
                acc[g4+0] = ww.x; acc[g4+1] = ww.y; acc[g4+2] = ww.z; acc[g4+3] = ww.w;
            }
        }
        for (int k = 0; k < HDIM; ++k) {
            float hk = hcol[k * 64];
            #pragma unroll
            for (int g4 = 0; g4 < NG; g4 += 4) {
                float4 w = *(const float4*)&sWhhT[k][g4];     // broadcast read
                acc[g4+0] = fmaf(hk, w.x, acc[g4+0]);
                acc[g4+1] = fmaf(hk, w.y, acc[g4+1]);
                acc[g4+2] = fmaf(hk, w.z, acc[g4+2]);
                acc[g4+3] = fmaf(hk, w.w, acc[g4+3]);
            }
        }

        // ---- LSTM cell (PyTorch gate order: i, f, g, o) ----
        #pragma unroll
        for (int j = 0; j < HDIM; ++j) {
            float ig = acc[j];
            float fg = acc[HDIM + j];
            float gg = acc[2*HDIM + j];
            float og = acc[3*HDIM + j];
            float si = 1.f / (1.f + expf(-ig));
            float sf = 1.f / (1.f + expf(-fg));
            float so = 1.f / (1.f + expf(-og));
            float tg = tanhf(gg);
            float cj = sf * c_state[j] + si * tg;
            c_state[j] = cj;
            hcol[j * 64] = so * tanhf(cj);
        }

        // ---- logits = h @ Wl.T + bl ----
        float l[NOUTC];
        {
            float hk = hcol[0];
            #pragma unroll
            for (int n4 = 0; n4 < NOUTC; n4 += 4) {
                float4 w = *(const float4*)&sWlT[0][n4];
                l[n4+0] = hk * w.x; l[n4+1] = hk * w.y;
                l[n4+2] = hk * w.z; l[n4+3] = hk * w.w;
            }
        }
        for (int k = 1; k < HDIM; ++k) {
            float hk = hcol[k * 64];
            #pragma unroll
            for (int n4 = 0; n4 < NOUTC; n4 += 4) {
                float4 w = *(const float4*)&sWlT[k][n4];
                l[n4+0] = fmaf(hk, w.x, l[n4+0]);
                l[n4+1] = fmaf(hk, w.y, l[n4+1]);
                l[n4+2] = fmaf(hk, w.z, l[n4+2]);
                l[n4+3] = fmaf(hk, w.w, l[n4+3]);
            }
        }
        #pragma unroll
        for (int n4 = 0; n4 < NOUTC; n4 += 4) {
            float4 bb = *(const float4*)&sBl[n4];
            l[n4+0] += bb.x; l[n4+1] += bb.y; l[n4+2] += bb.z; l[n4+3] += bb.w;
        }

        // ---- masked softmax + stochastic sample ----
        const int  cnt = (s + 1) >> 1;
        const bool odd = (s & 1) != 0;
        float m = -INFINITY;
        #pragma unroll
        for (int n = 0; n < NOUTC; ++n) {
            bool msk = odd ? (n < cnt) : (n >= NHID);
            if (msk) m = fmaxf(m, l[n]);
        }
        float e[NOUTC];
        float Z = 0.f;
        #pragma unroll
        for (int n = 0; n < NOUTC; ++n) {
            bool msk = odd ? (n < cnt) : (n >= NHID);
            float v = msk ? expf(l[n] - m) : 0.f;
            e[n] = v;
            Z += v;
        }
        const float r = rnd[s * BATCH + b];
        float cum = 0.f, pr = 0.f, p0 = 0.f;
        int a = 0;
        bool found = false;
        #pragma unroll
        for (int n = 0; n < NOUTC; ++n) {
            float p = e[n] / Z;            // IEEE div, mirrors reference
            if (n == 0) p0 = p;
            cum += p;
            if (!found && cum > r) { found = true; a = n; pr = p; }
        }
        if (!found) { a = 0; pr = p0; }    // argmax of all-False == 0

        sPr[tid][s]  = pr;
        sAct[tid][s] = (float)a;
        act = a;
    }

    __syncthreads();
    // Coalesced write-out: out0[(b,s)] = b*47+s ; out1 at offset BATCH*NSTEPS
    const int base = blockIdx.x * 64 * NSTEPS;
    for (int i = tid; i < 64 * NSTEPS; i += 64) {
        int rr = i / NSTEPS, ss = i - rr * NSTEPS;
        out[base + i]                              = sPr[rr][ss];
        out[(size_t)BATCH * NSTEPS + base + i]     = sAct[rr][ss];
    }
}

extern "C" void kernel_launch(void* const* d_in, const int* in_sizes, int n_in,
                              void* d_out, int out_size, void* d_ws, size_t ws_size,
                              hipStream_t stream) {
    const float* W_ih = (const float*)d_in[0];
    const float* W_hh = (const float*)d_in[1];
    const float* b_ih = (const float*)d_in[2];
    const float* b_hh = (const float*)d_in[3];
    const float* Wl   = (const float*)d_in[4];
    const float* bl   = (const float*)d_in[5];
    const float* rnd  = (const float*)d_in[6];
    float* o = (float*)d_out;

    policy_kernel<<<BATCH / 64, 64, 0, stream>>>(W_ih, W_hh, b_ih, b_hh, Wl, bl, rnd, o);
}

// Round 5
// 768.865 us; speedup vs baseline: 1.6989x; 1.6989x over previous
//
#include <hip/hip_runtime.h>
#include <math.h>

#define BATCH   16384
#define HD      24      // LSTM hidden size
#define NOUTC   24
#define NHID    16
#define NSTEPS  47
#define NG      96
#define WPG     4       // waves per 64-element group
#define JPW     6       // j-slots per wave (24/WPG)
#define GPW     24      // gates per wave

__global__ __launch_bounds__(256) void policy_kernel(
    const float* __restrict__ W_ih, const float* __restrict__ W_hh,
    const float* __restrict__ b_ih, const float* __restrict__ b_hh,
    const float* __restrict__ Wl,   const float* __restrict__ bl,
    const float* __restrict__ rnd,  float* __restrict__ out)
{
    __shared__ float sWihB[NG][25];          // [g][c] + bias folded; per-lane act gather (distinct banks)
    __shared__ float sBias[NG];              // b_ih + b_hh (step 0: a == 0)
    __shared__ float sWhhP[HD][WPG][GPW];    // [k][w][t*6+i] : gate g = t*24 + w*6 + i (uniform float4 reads)
    __shared__ float sWlP[HD][WPG][8];       // [k][w][i] : n = w*6+i (6 used, 2 pad for alignment)
    __shared__ float sBl[NOUTC];
    __shared__ float hbuf[2][HD][64];        // h double-buffered by step parity
    __shared__ float sMax[WPG][64];          // partial masked max
    __shared__ float sE[NOUTC][64];          // exp values
    __shared__ float sPr[64][NSTEPS + 2];    // stride 49 -> bank-spread staging
    __shared__ unsigned char sAct8[64][NSTEPS + 2];

    const int tid  = threadIdx.x;
    const int w    = tid >> 6;               // wave id 0..3
    const int lane = tid & 63;               // element within group
    const int b    = blockIdx.x * 64 + lane;

    // ---- staging (once per block) ----
    for (int i = tid; i < NG * HD; i += 256) {
        int g = i / HD, k = i % HD;
        float bs = b_ih[g] + b_hh[g];
        sWihB[g][k] = W_ih[i] + bs;          // column gather table, bias folded
        int t = g / 24, rem = g % 24, ww = rem / 6, ii = rem % 6;
        sWhhP[k][ww][t * 6 + ii] = W_hh[i];  // permuted so wave ww's 24 weights are contiguous per k
    }
    for (int i = tid; i < NOUTC * HD; i += 256) {
        int n = i / HD, k = i % HD;
        sWlP[k][n / 6][n % 6] = Wl[i];
    }
    if (tid < NG)    sBias[tid] = b_ih[tid] + b_hh[tid];
    if (tid < NOUTC) sBl[tid]   = bl[tid];
    for (int i = tid; i < HD * 64; i += 256) (&hbuf[0][0][0])[i] = 0.f;  // h0 = 0
    __syncthreads();

    float c_state[JPW];
    #pragma unroll
    for (int i = 0; i < JPW; ++i) c_state[i] = 0.f;
    int act = 0;

    for (int s = 0; s < NSTEPS; ++s) {
        const int par = s & 1;

        // ---- gates slice: acc[t*6+i] for gate g = t*24 + w*6 + i ----
        float acc[GPW];
        if (s == 0) {
            #pragma unroll
            for (int t = 0; t < 4; ++t)
                #pragma unroll
                for (int i = 0; i < 6; ++i)
                    acc[t * 6 + i] = sBias[t * 24 + w * 6 + i];
        } else {
            #pragma unroll
            for (int t = 0; t < 4; ++t)
                #pragma unroll
                for (int i = 0; i < 6; ++i)
                    acc[t * 6 + i] = sWihB[t * 24 + w * 6 + i][act];  // per-lane act: distinct banks
        }
        #pragma unroll
        for (int k = 0; k < HD; ++k) {
            float hk = hbuf[par][k][lane];                 // 64-wide, conflict-free
            const float* wp = &sWhhP[k][w][0];             // wave-uniform broadcast
            #pragma unroll
            for (int q = 0; q < GPW; q += 4) {
                float4 wv = *(const float4*)&wp[q];
                acc[q + 0] = fmaf(hk, wv.x, acc[q + 0]);
                acc[q + 1] = fmaf(hk, wv.y, acc[q + 1]);
                acc[q + 2] = fmaf(hk, wv.z, acc[q + 2]);
                acc[q + 3] = fmaf(hk, wv.w, acc[q + 3]);
            }
        }

        // ---- LSTM cell for own 6 j's; write new h to other parity buffer ----
        #pragma unroll
        for (int i = 0; i < JPW; ++i) {
            float ig = acc[i], fg = acc[6 + i], gg = acc[12 + i], og = acc[18 + i];
            float si = 1.f / (1.f + expf(-ig));
            float sf = 1.f / (1.f + expf(-fg));
            float so = 1.f / (1.f + expf(-og));
            float tg = tanhf(gg);
            float cj = sf * c_state[i] + si * tg;
            c_state[i] = cj;
            hbuf[1 - par][w * 6 + i][lane] = so * tanhf(cj);
        }
        __syncthreads();   // B: new h visible

        // ---- logits slice: n = w*6+i ----
        float l[JPW];
        {
            float hk = hbuf[1 - par][0][lane];
            const float* wp = &sWlP[0][w][0];
            float4 w0 = *(const float4*)&wp[0];
            float2 w1 = *(const float2*)&wp[4];
            l[0] = hk * w0.x; l[1] = hk * w0.y; l[2] = hk * w0.z;
            l[3] = hk * w0.w; l[4] = hk * w1.x; l[5] = hk * w1.y;
        }
        #pragma unroll
        for (int k = 1; k < HD; ++k) {
            float hk = hbuf[1 - par][k][lane];
            const float* wp = &sWlP[k][w][0];
            float4 w0 = *(const float4*)&wp[0];
            float2 w1 = *(const float2*)&wp[4];
            l[0] = fmaf(hk, w0.x, l[0]); l[1] = fmaf(hk, w0.y, l[1]);
            l[2] = fmaf(hk, w0.z, l[2]); l[3] = fmaf(hk, w0.w, l[3]);
            l[4] = fmaf(hk, w1.x, l[4]); l[5] = fmaf(hk, w1.y, l[5]);
        }
        #pragma unroll
        for (int i = 0; i < 6; ++i) l[i] += sBl[w * 6 + i];

        // ---- masked partial max ----
        const int  cnt = (s + 1) >> 1;
        const bool odd = (s & 1) != 0;
        float pm = -INFINITY;
        #pragma unroll
        for (int i = 0; i < 6; ++i) {
            int n = w * 6 + i;
            bool msk = odd ? (n < cnt) : (n >= NHID);
            if (msk) pm = fmaxf(pm, l[i]);
        }
        sMax[w][lane] = pm;
        __syncthreads();   // C: partial maxes visible

        float m = fmaxf(fmaxf(sMax[0][lane], sMax[1][lane]),
                        fmaxf(sMax[2][lane], sMax[3][lane]));   // exact regardless of order
        #pragma unroll
        for (int i = 0; i < 6; ++i) {
            int n = w * 6 + i;
            bool msk = odd ? (n < cnt) : (n >= NHID);
            sE[n][lane] = msk ? expf(l[i] - m) : 0.f;
        }
        __syncthreads();   // D: e's visible

        // ---- finish (redundant in all waves — identical IEEE ops => identical act) ----
        float e[NOUTC];
        #pragma unroll
        for (int n = 0; n < NOUTC; ++n) e[n] = sE[n][lane];
        float Z = 0.f;
        #pragma unroll
        for (int n = 0; n < NOUTC; ++n) Z += e[n];               // sequential, same order as ref path
        const float r = rnd[s * BATCH + b];
        float cum = 0.f, pr = 0.f, p0 = 0.f;
        int a = 0;
        bool found = false;
        #pragma unroll
        for (int n = 0; n < NOUTC; ++n) {
            float p = e[n] / Z;            // IEEE div, mirrors reference
            if (n == 0) p0 = p;
            cum += p;
            if (!found && cum > r) { found = true; a = n; pr = p; }
        }
        if (!found) { a = 0; pr = p0; }
        if (w == 0) { sPr[lane][s] = pr; sAct8[lane][s] = (unsigned char)a; }
        act = a;
    }

    __syncthreads();
    // ---- coalesced write-out ----
    const int base = blockIdx.x * 64 * NSTEPS;
    for (int i = tid; i < 64 * NSTEPS; i += 256) {
        int rr = i / NSTEPS, ss = i - rr * NSTEPS;
        out[base + i]                          = sPr[rr][ss];
        out[(size_t)BATCH * NSTEPS + base + i] = (float)sAct8[rr][ss];
    }
}

extern "C" void kernel_launch(void* const* d_in, const int* in_sizes, int n_in,
                              void* d_out, int out_size, void* d_ws, size_t ws_size,
                              hipStream_t stream) {
    const float* W_ih = (const float*)d_in[0];
    const float* W_hh = (const float*)d_in[1];
    const float* b_ih = (const float*)d_in[2];
    const float* b_hh = (const float*)d_in[3];
    const float* Wl   = (const float*)d_in[4];
    const float* bl   = (const float*)d_in[5];
    const float* rnd  = (const float*)d_in[6];
    float* o = (float*)d_out;

    policy_kernel<<<BATCH / 64, 256, 0, stream>>>(W_ih, W_hh, b_ih, b_hh, Wl, bl, rnd, o);
}

// Round 7
// 258.218 us; speedup vs baseline: 5.0585x; 2.9776x over previous
//
#include <hip/hip_runtime.h>
#include <math.h>

#define BATCH   16384
#define HD      24      // LSTM hidden size
#define NOUTC   24
#define NHID    16
#define NSTEPS  47
#define NG      96
#define WPG     12      // waves per 64-element group
#define JPW     2       // j-slots per wave (24/WPG)
#define GPW     8       // gates per wave (96/WPG)

__global__ __launch_bounds__(768) void policy_kernel(
    const float* __restrict__ W_ih, const float* __restrict__ W_hh,
    const float* __restrict__ b_ih, const float* __restrict__ b_hh,
    const float* __restrict__ Wl,   const float* __restrict__ bl,
    const float* __restrict__ rnd,  float* __restrict__ out)
{
    __shared__ float sWihB[NG][25];          // [g][c] + bias folded; per-lane act gather
    __shared__ float sBias[NG];              // b_ih + b_hh (step 0: a == 0)
    __shared__ float sWhhP[HD][WPG][GPW];    // [k][w][t*2+i] : gate g = t*24 + w*2 + i
    __shared__ float sWlP[HD][WPG][JPW];     // [k][w][i] : n = w*2+i
    __shared__ float sBl[NOUTC];
    __shared__ float hbuf[2][HD][64];        // h double-buffered by step parity
    __shared__ float sMax[WPG][64];          // partial masked max
    __shared__ float sE[NOUTC][64];          // exp values
    __shared__ float sPr[64][NSTEPS + 2];    // stride 49 -> bank-spread staging
    __shared__ unsigned char sAct8[64][NSTEPS + 2];

    const int tid  = threadIdx.x;
    const int w    = tid >> 6;               // wave id 0..11
    const int lane = tid & 63;               // element within group
    const int b    = blockIdx.x * 64 + lane;

    // ---- staging (once per block) ----
    for (int i = tid; i < NG * HD; i += 768) {
        int g = i / HD, k = i % HD;
        float bs = b_ih[g] + b_hh[g];
        sWihB[g][k] = W_ih[i] + bs;          // column gather table, bias folded
        int t = g / 24, rem = g % 24, ww = rem / JPW, ii = rem % JPW;
        sWhhP[k][ww][t * JPW + ii] = W_hh[i];
    }
    for (int i = tid; i < NOUTC * HD; i += 768) {
        int n = i / HD, k = i % HD;
        sWlP[k][n / JPW][n % JPW] = Wl[i];
    }
    if (tid < NG)    sBias[tid] = b_ih[tid] + b_hh[tid];
    if (tid < NOUTC) sBl[tid]   = bl[tid];
    for (int i = tid; i < HD * 64; i += 768) (&hbuf[0][0][0])[i] = 0.f;  // h0 = 0
    __syncthreads();

    float c_state[JPW];
    #pragma unroll
    for (int i = 0; i < JPW; ++i) c_state[i] = 0.f;
    int act = 0;

    for (int s = 0; s < NSTEPS; ++s) {
        const int par = s & 1;
        const float r = rnd[s * BATCH + b];   // issued early, used in finish

        // ---- gates slice: acc[t*2+i] for gate g = t*24 + w*2 + i ----
        float acc[GPW];
        if (s == 0) {
            #pragma unroll
            for (int t = 0; t < 4; ++t)
                #pragma unroll
                for (int i = 0; i < JPW; ++i)
                    acc[t * JPW + i] = sBias[t * 24 + w * JPW + i];
        } else {
            #pragma unroll
            for (int t = 0; t < 4; ++t)
                #pragma unroll
                for (int i = 0; i < JPW; ++i)
                    acc[t * JPW + i] = sWihB[t * 24 + w * JPW + i][act];
        }
        #pragma unroll 4
        for (int k = 0; k < HD; ++k) {
            float hk = hbuf[par][k][lane];                 // 64-wide, conflict-free
            const float* wp = &sWhhP[k][w][0];             // wave-uniform broadcast
            float4 w0 = *(const float4*)&wp[0];
            float4 w1 = *(const float4*)&wp[4];
            acc[0] = fmaf(hk, w0.x, acc[0]);
            acc[1] = fmaf(hk, w0.y, acc[1]);
            acc[2] = fmaf(hk, w0.z, acc[2]);
            acc[3] = fmaf(hk, w0.w, acc[3]);
            acc[4] = fmaf(hk, w1.x, acc[4]);
            acc[5] = fmaf(hk, w1.y, acc[5]);
            acc[6] = fmaf(hk, w1.z, acc[6]);
            acc[7] = fmaf(hk, w1.w, acc[7]);
        }

        // ---- LSTM cell for own 2 j's; write new h to other parity buffer ----
        #pragma unroll
        for (int i = 0; i < JPW; ++i) {
            float ig = acc[0 * JPW + i], fg = acc[1 * JPW + i];
            float gg = acc[2 * JPW + i], og = acc[3 * JPW + i];
            float si = 1.f / (1.f + expf(-ig));
            float sf = 1.f / (1.f + expf(-fg));
            float so = 1.f / (1.f + expf(-og));
            float tg = tanhf(gg);
            float cj = sf * c_state[i] + si * tg;
            c_state[i] = cj;
            hbuf[1 - par][w * JPW + i][lane] = so * tanhf(cj);
        }
        __syncthreads();   // B: new h visible

        // ---- logits slice: n = w*2+i ----
        float l[JPW];
        {
            float hk = hbuf[1 - par][0][lane];
            const float* wp = &sWlP[0][w][0];
            float2 wv = *(const float2*)&wp[0];
            l[0] = hk * wv.x; l[1] = hk * wv.y;
        }
        #pragma unroll 4
        for (int k = 1; k < HD; ++k) {
            float hk = hbuf[1 - par][k][lane];
            const float* wp = &sWlP[k][w][0];
            float2 wv = *(const float2*)&wp[0];
            l[0] = fmaf(hk, wv.x, l[0]);
            l[1] = fmaf(hk, wv.y, l[1]);
        }
        #pragma unroll
        for (int i = 0; i < JPW; ++i) l[i] += sBl[w * JPW + i];

        // ---- masked partial max ----
        const int  cnt = (s + 1) >> 1;
        const bool odd = (s & 1) != 0;
        float pm = -INFINITY;
        #pragma unroll
        for (int i = 0; i < JPW; ++i) {
            int n = w * JPW + i;
            bool msk = odd ? (n < cnt) : (n >= NHID);
            if (msk) pm = fmaxf(pm, l[i]);
        }
        sMax[w][lane] = pm;
        __syncthreads();   // C: partial maxes visible

        float m = sMax[0][lane];
        #pragma unroll
        for (int q = 1; q < WPG; ++q) m = fmaxf(m, sMax[q][lane]);  // max exact, order-free
        #pragma unroll
        for (int i = 0; i < JPW; ++i) {
            int n = w * JPW + i;
            bool msk = odd ? (n < cnt) : (n >= NHID);
            sE[n][lane] = msk ? expf(l[i] - m) : 0.f;
        }
        __syncthreads();   // D: e's visible

        // ---- finish (redundant in all waves — identical IEEE ops => identical act) ----
        float e[NOUTC];
        #pragma unroll
        for (int n = 0; n < NOUTC; ++n) e[n] = sE[n][lane];
        float Z = 0.f;
        #pragma unroll
        for (int n = 0; n < NOUTC; ++n) Z += e[n];               // sequential 0..23
        float cum = 0.f, pr = 0.f, p0 = 0.f;
        int a = 0;
        bool found = false;
        #pragma unroll
        for (int n = 0; n < NOUTC; ++n) {
            float p = e[n] / Z;            // IEEE div, mirrors reference
            if (n == 0) p0 = p;
            cum += p;
            if (!found && cum > r) { found = true; a = n; pr = p; }
        }
        if (!found) { a = 0; pr = p0; }
        if (w == 0) { sPr[lane][s] = pr; sAct8[lane][s] = (unsigned char)a; }
        act = a;
    }

    __syncthreads();
    // ---- coalesced write-out ----
    const int base = blockIdx.x * 64 * NSTEPS;
    for (int i = tid; i < 64 * NSTEPS; i += 768) {
        int rr = i / NSTEPS, ss = i - rr * NSTEPS;
        out[base + i]                          = sPr[rr][ss];
        out[(size_t)BATCH * NSTEPS + base + i] = (float)sAct8[rr][ss];
    }
}

extern "C" void kernel_launch(void* const* d_in, const int* in_sizes, int n_in,
                              void* d_out, int out_size, void* d_ws, size_t ws_size,
                              hipStream_t stream) {
    const float* W_ih = (const float*)d_in[0];
    const float* W_hh = (const float*)d_in[1];
    const float* b_ih = (const float*)d_in[2];
    const float* b_hh = (const float*)d_in[3];
    const float* Wl   = (const float*)d_in[4];
    const float* bl   = (const float*)d_in[5];
    const float* rnd  = (const float*)d_in[6];
    float* o = (float*)d_out;

    policy_kernel<<<BATCH / 64, 768, 0, stream>>>(W_ih, W_hh, b_ih, b_hh, Wl, bl, rnd, o);
}

// Round 8
// 230.518 us; speedup vs baseline: 5.6663x; 1.1202x over previous
//
#include <hip/hip_runtime.h>
#include <math.h>

#define BATCH   16384
#define HD      24      // LSTM hidden size
#define NOUTC   24
#define NHID    16
#define NSTEPS  47
#define NG      96
#define WPG     12      // waves per 64-element group
#define JPW     2       // j-slots per wave (24/WPG)
#define GPW     8       // gates per wave (96/WPG)

__device__ __forceinline__ float fast_sigmoid(float x) {
    float t = __expf(-x);                       // v_exp-based, branch-free
    return __builtin_amdgcn_rcpf(1.0f + t);     // v_rcp_f32, ~1 ulp
}
__device__ __forceinline__ float fast_tanh(float x) {
    float ax = fabsf(x);
    float t  = __expf(-2.0f * ax);
    float r  = (1.0f - t) * __builtin_amdgcn_rcpf(1.0f + t);
    return copysignf(r, x);
}

__global__ __launch_bounds__(768) void policy_kernel(
    const float* __restrict__ W_ih, const float* __restrict__ W_hh,
    const float* __restrict__ b_ih, const float* __restrict__ b_hh,
    const float* __restrict__ Wl,   const float* __restrict__ bl,
    const float* __restrict__ rnd,  float* __restrict__ out)
{
    __shared__ float sWihB[NG][25];          // [g][c] + bias folded; per-lane act gather
    __shared__ float sBias[NG];              // b_ih + b_hh (step 0: a == 0)
    __shared__ float sWhhP[HD][WPG][GPW];    // [k][w][t*2+i] : gate g = t*24 + w*2 + i
    __shared__ float sWlP[HD][WPG][JPW];     // [k][w][i] : n = w*2+i
    __shared__ float sBl[NOUTC];
    __shared__ float hbuf[2][HD][64];        // h double-buffered by step parity
    __shared__ float sMax[WPG][64];          // partial masked max
    __shared__ float sE[NOUTC][64];          // exp values
    __shared__ float sP[NOUTC][64];          // p = e/Z (wave-parallel IEEE divides)
    __shared__ float sPr[64][NSTEPS + 2];    // stride 49 -> bank-spread staging
    __shared__ unsigned char sAct8[64][NSTEPS + 2];

    const int tid  = threadIdx.x;
    const int w    = tid >> 6;               // wave id 0..11
    const int lane = tid & 63;               // element within group
    const int b    = blockIdx.x * 64 + lane;

    // ---- staging (once per block) ----
    for (int i = tid; i < NG * HD; i += 768) {
        int g = i / HD, k = i % HD;
        float bs = b_ih[g] + b_hh[g];
        sWihB[g][k] = W_ih[i] + bs;          // column gather table, bias folded
        int t = g / 24, rem = g % 24, ww = rem / JPW, ii = rem % JPW;
        sWhhP[k][ww][t * JPW + ii] = W_hh[i];
    }
    for (int i = tid; i < NOUTC * HD; i += 768) {
        int n = i / HD, k = i % HD;
        sWlP[k][n / JPW][n % JPW] = Wl[i];
    }
    if (tid < NG)    sBias[tid] = b_ih[tid] + b_hh[tid];
    if (tid < NOUTC) sBl[tid]   = bl[tid];
    for (int i = tid; i < HD * 64; i += 768) (&hbuf[0][0][0])[i] = 0.f;  // h0 = 0
    __syncthreads();

    float c_state[JPW];
    #pragma unroll
    for (int i = 0; i < JPW; ++i) c_state[i] = 0.f;
    int act = 0;

    for (int s = 0; s < NSTEPS; ++s) {
        const int par = s & 1;
        const float r = rnd[s * BATCH + b];   // issued early, used in finish

        // ---- gates slice: acc[t*2+i] for gate g = t*24 + w*2 + i ----
        float acc[GPW];
        if (s == 0) {
            #pragma unroll
            for (int t = 0; t < 4; ++t)
                #pragma unroll
                for (int i = 0; i < JPW; ++i)
                    acc[t * JPW + i] = sBias[t * 24 + w * JPW + i];
        } else {
            #pragma unroll
            for (int t = 0; t < 4; ++t)
                #pragma unroll
                for (int i = 0; i < JPW; ++i)
                    acc[t * JPW + i] = sWihB[t * 24 + w * JPW + i][act];
        }
        #pragma unroll 4
        for (int k = 0; k < HD; ++k) {
            float hk = hbuf[par][k][lane];                 // 64-wide, conflict-free
            const float* wp = &sWhhP[k][w][0];             // wave-uniform broadcast
            float4 w0 = *(const float4*)&wp[0];
            float4 w1 = *(const float4*)&wp[4];
            acc[0] = fmaf(hk, w0.x, acc[0]);
            acc[1] = fmaf(hk, w0.y, acc[1]);
            acc[2] = fmaf(hk, w0.z, acc[2]);
            acc[3] = fmaf(hk, w0.w, acc[3]);
            acc[4] = fmaf(hk, w1.x, acc[4]);
            acc[5] = fmaf(hk, w1.y, acc[5]);
            acc[6] = fmaf(hk, w1.z, acc[6]);
            acc[7] = fmaf(hk, w1.w, acc[7]);
        }

        // ---- LSTM cell for own 2 j's; write new h to other parity buffer ----
        #pragma unroll
        for (int i = 0; i < JPW; ++i) {
            float ig = acc[0 * JPW + i], fg = acc[1 * JPW + i];
            float gg = acc[2 * JPW + i], og = acc[3 * JPW + i];
            float si = fast_sigmoid(ig);
            float sf = fast_sigmoid(fg);
            float so = fast_sigmoid(og);
            float tg = fast_tanh(gg);
            float cj = sf * c_state[i] + si * tg;
            c_state[i] = cj;
            hbuf[1 - par][w * JPW + i][lane] = so * fast_tanh(cj);
        }
        __syncthreads();   // B: new h visible

        // ---- logits slice: n = w*2+i ----
        float l[JPW];
        {
            float hk = hbuf[1 - par][0][lane];
            const float* wp = &sWlP[0][w][0];
            float2 wv = *(const float2*)&wp[0];
            l[0] = hk * wv.x; l[1] = hk * wv.y;
        }
        #pragma unroll 4
        for (int k = 1; k < HD; ++k) {
            float hk = hbuf[1 - par][k][lane];
            const float* wp = &sWlP[k][w][0];
            float2 wv = *(const float2*)&wp[0];
            l[0] = fmaf(hk, wv.x, l[0]);
            l[1] = fmaf(hk, wv.y, l[1]);
        }
        #pragma unroll
        for (int i = 0; i < JPW; ++i) l[i] += sBl[w * JPW + i];

        // ---- masked partial max ----
        const int  cnt = (s + 1) >> 1;
        const bool odd = (s & 1) != 0;
        float pm = -INFINITY;
        #pragma unroll
        for (int i = 0; i < JPW; ++i) {
            int n = w * JPW + i;
            bool msk = odd ? (n < cnt) : (n >= NHID);
            if (msk) pm = fmaxf(pm, l[i]);
        }
        sMax[w][lane] = pm;
        __syncthreads();   // C: partial maxes visible

        float m = sMax[0][lane];
        #pragma unroll
        for (int q = 1; q < WPG; ++q) m = fmaxf(m, sMax[q][lane]);  // max exact, order-free
        #pragma unroll
        for (int i = 0; i < JPW; ++i) {
            int n = w * JPW + i;
            bool msk = odd ? (n < cnt) : (n >= NHID);
            sE[n][lane] = msk ? __expf(l[i] - m) : 0.f;
        }
        __syncthreads();   // D: e's visible

        // ---- wave-parallel IEEE divides: wave w owns p[2w],p[2w+1] ----
        {
            float Z = 0.f;
            #pragma unroll
            for (int n = 0; n < NOUTC; ++n) Z += sE[n][lane];   // same 0..23 order in every wave -> identical bits
            #pragma unroll
            for (int i = 0; i < JPW; ++i) {
                int n = w * JPW + i;
                sP[n][lane] = sE[n][lane] / Z;                  // IEEE div, mirrors reference
            }
        }
        __syncthreads();   // E: p's visible

        // ---- finish: cumsum over shared p's (identical in all waves) ----
        float cum = 0.f, pr = 0.f, p0 = 0.f;
        int a = 0;
        bool found = false;
        #pragma unroll
        for (int n = 0; n < NOUTC; ++n) {
            float p = sP[n][lane];
            if (n == 0) p0 = p;
            cum += p;
            if (!found && cum > r) { found = true; a = n; pr = p; }
        }
        if (!found) { a = 0; pr = p0; }
        if (w == 0) { sPr[lane][s] = pr; sAct8[lane][s] = (unsigned char)a; }
        act = a;
    }

    __syncthreads();
    // ---- coalesced write-out ----
    const int base = blockIdx.x * 64 * NSTEPS;
    for (int i = tid; i < 64 * NSTEPS; i += 768) {
        int rr = i / NSTEPS, ss = i - rr * NSTEPS;
        out[base + i]                          = sPr[rr][ss];
        out[(size_t)BATCH * NSTEPS + base + i] = (float)sAct8[rr][ss];
    }
}

extern "C" void kernel_launch(void* const* d_in, const int* in_sizes, int n_in,
                              void* d_out, int out_size, void* d_ws, size_t ws_size,
                              hipStream_t stream) {
    const float* W_ih = (const float*)d_in[0];
    const float* W_hh = (const float*)d_in[1];
    const float* b_ih = (const float*)d_in[2];
    const float* b_hh = (const float*)d_in[3];
    const float* Wl   = (const float*)d_in[4];
    const float* bl   = (const float*)d_in[5];
    const float* rnd  = (const float*)d_in[6];
    float* o = (float*)d_out;

    policy_kernel<<<BATCH / 64, 768, 0, stream>>>(W_ih, W_hh, b_ih, b_hh, Wl, bl, rnd, o);
}